// Round 1
// baseline (567.199 us; speedup 1.0000x reference)
//
#include <hip/hip_runtime.h>

#define DIM 128

// ---------------- graph build ----------------
__global__ void k_count(const int* __restrict__ col, int E, int* __restrict__ cnt){
  int i = blockIdx.x*blockDim.x + threadIdx.x;
  if (i < E) atomicAdd(&cnt[col[i]], 1);
}

__global__ void k_scan1(const int* __restrict__ cnt, int* __restrict__ off,
                        int* __restrict__ bsum, int N){
  __shared__ int s[256];
  int i = blockIdx.x*256 + threadIdx.x;
  int v = (i < N) ? cnt[i] : 0;
  s[threadIdx.x] = v;
  __syncthreads();
  for (int d = 1; d < 256; d <<= 1){
    int t = (threadIdx.x >= d) ? s[threadIdx.x - d] : 0;
    __syncthreads();
    s[threadIdx.x] += t;
    __syncthreads();
  }
  if (i < N) off[i] = s[threadIdx.x] - v;       // exclusive within block
  if (threadIdx.x == 255) bsum[blockIdx.x] = s[255];
}

__global__ void k_scan2(int* __restrict__ bsum, int nb){
  __shared__ int s[512];
  int t = threadIdx.x;
  int v = (t < nb) ? bsum[t] : 0;
  s[t] = v;
  __syncthreads();
  for (int d = 1; d < 512; d <<= 1){
    int x = (t >= d) ? s[t - d] : 0;
    __syncthreads();
    s[t] += x;
    __syncthreads();
  }
  if (t < nb) bsum[t] = s[t] - v;               // exclusive block offsets
}

__global__ void k_scan3(int* __restrict__ off, const int* __restrict__ bsum,
                        const int* __restrict__ cnt, float* __restrict__ dinv, int N){
  int i = blockIdx.x*blockDim.x + threadIdx.x;
  if (i < N){
    off[i] += bsum[i >> 8];
    dinv[i] = rsqrtf((float)(cnt[i] + 1));      // +1 self-loop
  }
}

__global__ void k_scatter(const int* __restrict__ row, const int* __restrict__ col, int E,
                          const int* __restrict__ off, int* __restrict__ cursor,
                          int* __restrict__ csr_row){
  int e = blockIdx.x*blockDim.x + threadIdx.x;
  if (e < E){
    int c = col[e];
    int pos = off[c] + atomicAdd(&cursor[c], 1);
    csr_row[pos] = row[e];
  }
}

// ---------------- GEMM: Y[N,128] = (relu?)X[N,128] @ W[128,128] (+ addvec) ----------------
__global__ __launch_bounds__(256) void k_gemm(const float* __restrict__ X,
                                              const float* __restrict__ W,
                                              const float* __restrict__ addvec,
                                              float* __restrict__ Y, int N, int doRelu){
  __shared__ float Xs[64][DIM];   // 32 KB
  __shared__ float Ws[64][DIM];   // 32 KB (K-chunked)
  int tx = threadIdx.x & 31;      // 4 output cols
  int ty = threadIdx.x >> 5;      // 8 rows each
  int rb = blockIdx.x * 64;

  #pragma unroll
  for (int i = 0; i < 8; i++){
    int f4 = i*256 + threadIdx.x;               // [0,2048) float4 slots
    int r  = f4 >> 5;
    int cc = (f4 & 31) * 4;
    float4 val = make_float4(0.f, 0.f, 0.f, 0.f);
    if (rb + r < N) val = *(const float4*)(X + (size_t)(rb + r)*DIM + cc);
    if (doRelu){
      val.x = fmaxf(val.x, 0.f); val.y = fmaxf(val.y, 0.f);
      val.z = fmaxf(val.z, 0.f); val.w = fmaxf(val.w, 0.f);
    }
    *(float4*)(&Xs[r][cc]) = val;
  }

  float acc[8][4];
  #pragma unroll
  for (int r8 = 0; r8 < 8; r8++){ acc[r8][0]=0.f; acc[r8][1]=0.f; acc[r8][2]=0.f; acc[r8][3]=0.f; }

  #pragma unroll
  for (int kc = 0; kc < DIM; kc += 64){
    __syncthreads();
    #pragma unroll
    for (int i = 0; i < 8; i++){
      int f4 = i*256 + threadIdx.x;
      int r  = f4 >> 5;
      int cc = (f4 & 31) * 4;
      *(float4*)(&Ws[r][cc]) = *(const float4*)(W + (size_t)(kc + r)*DIM + cc);
    }
    __syncthreads();
    #pragma unroll 4
    for (int k = 0; k < 64; k++){
      float4 w4 = *(const float4*)(&Ws[k][tx*4]);
      #pragma unroll
      for (int r8 = 0; r8 < 8; r8++){
        float xv = Xs[ty*8 + r8][kc + k];
        acc[r8][0] += xv*w4.x; acc[r8][1] += xv*w4.y;
        acc[r8][2] += xv*w4.z; acc[r8][3] += xv*w4.w;
      }
    }
  }

  float4 av = make_float4(0.f, 0.f, 0.f, 0.f);
  if (addvec) av = *(const float4*)(addvec + tx*4);
  #pragma unroll
  for (int r8 = 0; r8 < 8; r8++){
    int r = rb + ty*8 + r8;
    if (r < N){
      float4 o;
      o.x = acc[r8][0] + av.x; o.y = acc[r8][1] + av.y;
      o.z = acc[r8][2] + av.z; o.w = acc[r8][3] + av.w;
      *(float4*)(Y + (size_t)r*DIM + tx*4) = o;
    }
  }
}

// ---------------- conv aggregate: one wave per node, 2 f32/lane ----------------
__global__ void k_conv1(const float* __restrict__ xw, const int* __restrict__ csr_row,
                        const int* __restrict__ off, const int* __restrict__ cnt,
                        const float* __restrict__ dinv, const float* __restrict__ b,
                        float* __restrict__ out, int N){
  int wid  = (blockIdx.x*blockDim.x + threadIdx.x) >> 6;
  int lane = threadIdx.x & 63;
  if (wid >= N) return;
  int v = __builtin_amdgcn_readfirstlane(wid);
  float dv = dinv[v];
  float2 self = *(const float2*)(xw + (size_t)v*DIM + lane*2);
  float ax = dv*self.x, ay = dv*self.y;        // self-loop (x dv again at end)
  int o0 = off[v], c = cnt[v];
  for (int i = 0; i < c; i++){
    int r = csr_row[o0 + i];
    float dr = dinv[r];
    float2 xr = *(const float2*)(xw + (size_t)r*DIM + lane*2);
    ax += dr*xr.x; ay += dr*xr.y;
  }
  float2 bb = *(const float2*)(b + lane*2);
  float2 res; res.x = dv*ax + bb.x; res.y = dv*ay + bb.y;
  *(float2*)(out + (size_t)v*DIM + lane*2) = res;
}

// c[j] = relu(posts[root]) @ W2[128:256]; cpool = pooled const cols + raw cr[126..127]
__global__ void k_small(const float* __restrict__ posts, const float* __restrict__ W2,
                        const float* __restrict__ conv1_out, const int* __restrict__ rootIdx,
                        float* __restrict__ cvec, float* __restrict__ cpool){
  int j = threadIdx.x;                          // 128 threads
  int root = rootIdx[0];
  __shared__ float pr[DIM];
  __shared__ float cr[DIM];
  pr[j] = fmaxf(posts[(size_t)root*DIM + j], 0.f);
  cr[j] = conv1_out[(size_t)root*DIM + j];
  __syncthreads();
  float s = 0.f;
  #pragma unroll 4
  for (int k = 0; k < DIM; k++) s += pr[k] * W2[(size_t)(DIM + k)*DIM + j];
  cvec[j] = s;
  cpool[j] = (j < 126) ? (cr[j] + cr[j+1] + cr[j+2]) * (1.f/3.f) : cr[j];
}

// conv2 aggregate + relu + fused avg-pool -> final out [N,254]
__global__ void k_conv2(const float* __restrict__ xw2, const int* __restrict__ csr_row,
                        const int* __restrict__ off, const int* __restrict__ cnt,
                        const float* __restrict__ dinv, const float* __restrict__ b2,
                        const float* __restrict__ cpool, float* __restrict__ out, int N){
  int wid  = (blockIdx.x*blockDim.x + threadIdx.x) >> 6;
  int lane = threadIdx.x & 63;
  if (wid >= N) return;
  int v = __builtin_amdgcn_readfirstlane(wid);
  float dv = dinv[v];
  float2 self = *(const float2*)(xw2 + (size_t)v*DIM + lane*2);
  float ax = dv*self.x, ay = dv*self.y;
  int o0 = off[v], c = cnt[v];
  for (int i = 0; i < c; i++){
    int r = csr_row[o0 + i];
    float dr = dinv[r];
    float2 xr = *(const float2*)(xw2 + (size_t)r*DIM + lane*2);
    ax += dr*xr.x; ay += dr*xr.y;
  }
  float2 bb = *(const float2*)(b2 + lane*2);
  float o0v = fmaxf(dv*ax + bb.x, 0.f);        // conv2_out[v][2*lane]
  float o1v = fmaxf(dv*ay + bb.y, 0.f);        // conv2_out[v][2*lane+1]

  // pooling: f = [conv1_root(128) | conv2_out(128)]; out col j = mean(f[j..j+2])
  float pa = __shfl_up(o0v, 1);                // o[2l-2]
  float pb = __shfl_up(o1v, 1);                // o[2l-1]
  if (lane == 0){ pa = cpool[126]; pb = cpool[127]; }   // cr[126], cr[127]
  float p0 = (pa + pb + o0v) * (1.f/3.f);      // col 126+2l
  float p1 = (pb + o0v + o1v) * (1.f/3.f);     // col 127+2l

  float* orow = out + (size_t)v*254;
  if (lane < 63){                               // const cols 0..125
    float2 cp = *(const float2*)(cpool + 2*lane);
    *(float2*)(orow + 2*lane) = cp;
  }
  *(float2*)(orow + 126 + 2*lane) = make_float2(p0, p1);
}

extern "C" void kernel_launch(void* const* d_in, const int* in_sizes, int n_in,
                              void* d_out, int out_size, void* d_ws, size_t ws_size,
                              hipStream_t stream){
  const float* posts = (const float*)d_in[0];
  const float* W1    = (const float*)d_in[1];
  const float* b1    = (const float*)d_in[2];
  const float* W2    = (const float*)d_in[3];
  const float* b2    = (const float*)d_in[4];
  const int*   eidx  = (const int*)d_in[5];
  const int*   rootI = (const int*)d_in[6];
  int N = in_sizes[0] / DIM;
  int E = in_sizes[5] / 2;
  const int* row = eidx;
  const int* col = eidx + E;

  char* p = (char*)d_ws;
  auto alloc = [&](size_t bytes)->void*{
    void* q = (void*)p; p += (bytes + 255) & ~(size_t)255; return q;
  };
  float* xw1    = (float*)alloc((size_t)N*DIM*4);
  float* c1out  = (float*)alloc((size_t)N*DIM*4);
  float* xw2    = (float*)alloc((size_t)N*DIM*4);
  float* dinv   = (float*)alloc((size_t)N*4);
  float* cvec   = (float*)alloc(DIM*4);
  float* cpool  = (float*)alloc(DIM*4);
  int*   cnt    = (int*)alloc((size_t)N*4);
  int*   off    = (int*)alloc((size_t)N*4);
  int*   cursor = (int*)alloc((size_t)N*4);
  int*   bsum   = (int*)alloc(512*4);
  int*   csrrow = (int*)alloc((size_t)E*4);

  hipMemsetAsync(cnt,    0, (size_t)N*4, stream);
  hipMemsetAsync(cursor, 0, (size_t)N*4, stream);

  int nb = (N + 255) / 256;
  k_count  <<<(E + 255)/256, 256, 0, stream>>>(col, E, cnt);
  k_scan1  <<<nb, 256, 0, stream>>>(cnt, off, bsum, N);
  k_scan2  <<<1, 512, 0, stream>>>(bsum, nb);
  k_scan3  <<<nb, 256, 0, stream>>>(off, bsum, cnt, dinv, N);
  k_scatter<<<(E + 255)/256, 256, 0, stream>>>(row, col, E, off, cursor, csrrow);

  k_gemm <<<(N + 63)/64, 256, 0, stream>>>(posts, W1, nullptr, xw1, N, 0);
  k_conv1<<<(N + 3)/4, 256, 0, stream>>>(xw1, csrrow, off, cnt, dinv, b1, c1out, N);
  k_small<<<1, 128, 0, stream>>>(posts, W2, c1out, rootI, cvec, cpool);
  k_gemm <<<(N + 63)/64, 256, 0, stream>>>(c1out, W2, cvec, xw2, N, 1);
  k_conv2<<<(N + 3)/4, 256, 0, stream>>>(xw2, csrrow, off, cnt, dinv, b2, cpool,
                                         (float*)d_out, N);
}

// Round 3
// 422.930 us; speedup vs baseline: 1.3411x; 1.3411x over previous
//
#include <hip/hip_runtime.h>
#include <hip/hip_fp16.h>

#define DIM 128

// ---------------- graph build ----------------
__global__ void k_count(const int* __restrict__ col, int E, int* __restrict__ cnt){
  int i = blockIdx.x*blockDim.x + threadIdx.x;
  if (i < E) atomicAdd(&cnt[col[i]], 1);
}

__global__ void k_scan1(const int* __restrict__ cnt, int* __restrict__ off,
                        int* __restrict__ bsum, int N){
  __shared__ int s[256];
  int i = blockIdx.x*256 + threadIdx.x;
  int v = (i < N) ? cnt[i] : 0;
  s[threadIdx.x] = v;
  __syncthreads();
  for (int d = 1; d < 256; d <<= 1){
    int t = (threadIdx.x >= d) ? s[threadIdx.x - d] : 0;
    __syncthreads();
    s[threadIdx.x] += t;
    __syncthreads();
  }
  if (i < N) off[i] = s[threadIdx.x] - v;       // exclusive within block
  if (threadIdx.x == 255) bsum[blockIdx.x] = s[255];
}

__global__ void k_scan2(int* __restrict__ bsum, int nb){
  __shared__ int s[512];
  int t = threadIdx.x;
  int v = (t < nb) ? bsum[t] : 0;
  s[t] = v;
  __syncthreads();
  for (int d = 1; d < 512; d <<= 1){
    int x = (t >= d) ? s[t - d] : 0;
    __syncthreads();
    s[t] += x;
    __syncthreads();
  }
  if (t < nb) bsum[t] = s[t] - v;               // exclusive block offsets
}

__global__ void k_scan3(int* __restrict__ off, const int* __restrict__ bsum,
                        const int* __restrict__ cnt, float* __restrict__ dinv, int N){
  int i = blockIdx.x*blockDim.x + threadIdx.x;
  if (i < N){
    off[i] += bsum[i >> 8];
    dinv[i] = rsqrtf((float)(cnt[i] + 1));      // +1 self-loop
  }
}

__global__ void k_scatter(const int* __restrict__ row, const int* __restrict__ col, int E,
                          const int* __restrict__ off, int* __restrict__ cursor,
                          int* __restrict__ csr_row){
  int e = blockIdx.x*blockDim.x + threadIdx.x;
  if (e < E){
    int c = col[e];
    int pos = off[c] + atomicAdd(&cursor[c], 1);
    csr_row[pos] = row[e];
  }
}

// ---- GEMM: Yh[N,128](fp16) = dinv[r] * ( (relu?)X[N,128] @ W[128,128] + addvec ) ----
__global__ __launch_bounds__(256) void k_gemm(const float* __restrict__ X,
                                              const float* __restrict__ W,
                                              const float* __restrict__ addvec,
                                              const float* __restrict__ dinv,
                                              __half* __restrict__ Yh, int N, int doRelu){
  __shared__ float Xs[64][DIM];   // 32 KB
  __shared__ float Ws[64][DIM];   // 32 KB (K-chunked)
  int tx = threadIdx.x & 31;      // 4 output cols
  int ty = threadIdx.x >> 5;      // 8 rows each
  int rb = blockIdx.x * 64;

  #pragma unroll
  for (int i = 0; i < 8; i++){
    int f4 = i*256 + threadIdx.x;               // [0,2048) float4 slots
    int r  = f4 >> 5;
    int cc = (f4 & 31) * 4;
    float4 val = make_float4(0.f, 0.f, 0.f, 0.f);
    if (rb + r < N) val = *(const float4*)(X + (size_t)(rb + r)*DIM + cc);
    if (doRelu){
      val.x = fmaxf(val.x, 0.f); val.y = fmaxf(val.y, 0.f);
      val.z = fmaxf(val.z, 0.f); val.w = fmaxf(val.w, 0.f);
    }
    *(float4*)(&Xs[r][cc]) = val;
  }

  float acc[8][4];
  #pragma unroll
  for (int r8 = 0; r8 < 8; r8++){ acc[r8][0]=0.f; acc[r8][1]=0.f; acc[r8][2]=0.f; acc[r8][3]=0.f; }

  #pragma unroll
  for (int kc = 0; kc < DIM; kc += 64){
    __syncthreads();
    #pragma unroll
    for (int i = 0; i < 8; i++){
      int f4 = i*256 + threadIdx.x;
      int r  = f4 >> 5;
      int cc = (f4 & 31) * 4;
      *(float4*)(&Ws[r][cc]) = *(const float4*)(W + (size_t)(kc + r)*DIM + cc);
    }
    __syncthreads();
    #pragma unroll 4
    for (int k = 0; k < 64; k++){
      float4 w4 = *(const float4*)(&Ws[k][tx*4]);
      #pragma unroll
      for (int r8 = 0; r8 < 8; r8++){
        float xv = Xs[ty*8 + r8][kc + k];
        acc[r8][0] += xv*w4.x; acc[r8][1] += xv*w4.y;
        acc[r8][2] += xv*w4.z; acc[r8][3] += xv*w4.w;
      }
    }
  }

  float4 av = make_float4(0.f, 0.f, 0.f, 0.f);
  if (addvec) av = *(const float4*)(addvec + tx*4);
  #pragma unroll
  for (int r8 = 0; r8 < 8; r8++){
    int r = rb + ty*8 + r8;
    if (r < N){
      float dv = dinv[r];
      float4 o;
      o.x = dv*(acc[r8][0] + av.x); o.y = dv*(acc[r8][1] + av.y);
      o.z = dv*(acc[r8][2] + av.z); o.w = dv*(acc[r8][3] + av.w);
      __half2 h01 = __floats2half2_rn(o.x, o.y);
      __half2 h23 = __floats2half2_rn(o.z, o.w);
      uint2 u = make_uint2(*(unsigned int*)&h01, *(unsigned int*)&h23);
      *(uint2*)(Yh + (size_t)r*DIM + tx*4) = u;
    }
  }
}

// ---------------- conv1 aggregate: one wave/node, fp16 pre-scaled gather ----------------
__global__ void k_conv1(const __half* __restrict__ xws, const int* __restrict__ csr_row,
                        const int* __restrict__ off, const int* __restrict__ cnt,
                        const float* __restrict__ dinv, const float* __restrict__ b,
                        float* __restrict__ out, int N){
  int wid  = (blockIdx.x*blockDim.x + threadIdx.x) >> 6;
  int lane = threadIdx.x & 63;
  if (wid >= N) return;
  int v = __builtin_amdgcn_readfirstlane(wid);
  float dv = dinv[v];
  const __half2* base = (const __half2*)xws;    // row stride = 64 half2
  float2 s = __half22float2(base[(size_t)v*64 + lane]);   // self (pre-scaled)
  float ax = s.x, ay = s.y;
  int o0 = off[v], c = cnt[v];
  int i = 0;
  for (; i + 4 <= c; i += 4){
    int r0 = csr_row[o0+i+0], r1 = csr_row[o0+i+1];
    int r2 = csr_row[o0+i+2], r3 = csr_row[o0+i+3];
    float2 f0 = __half22float2(base[(size_t)r0*64 + lane]);
    float2 f1 = __half22float2(base[(size_t)r1*64 + lane]);
    float2 f2 = __half22float2(base[(size_t)r2*64 + lane]);
    float2 f3 = __half22float2(base[(size_t)r3*64 + lane]);
    ax += (f0.x + f1.x) + (f2.x + f3.x);
    ay += (f0.y + f1.y) + (f2.y + f3.y);
  }
  for (; i < c; i++){
    int r = csr_row[o0+i];
    float2 f = __half22float2(base[(size_t)r*64 + lane]);
    ax += f.x; ay += f.y;
  }
  float2 bb = *(const float2*)(b + lane*2);
  float2 res; res.x = dv*ax + bb.x; res.y = dv*ay + bb.y;
  *(float2*)(out + (size_t)v*DIM + lane*2) = res;
}

// c[j] = relu(posts[root]) @ W2[128:256]; cpool = pooled const cols + raw cr[126..127]
__global__ void k_small(const float* __restrict__ posts, const float* __restrict__ W2,
                        const float* __restrict__ conv1_out, const int* __restrict__ rootIdx,
                        float* __restrict__ cvec, float* __restrict__ cpool){
  int j = threadIdx.x;                          // 128 threads
  int root = rootIdx[0];
  __shared__ float pr[DIM];
  __shared__ float cr[DIM];
  pr[j] = fmaxf(posts[(size_t)root*DIM + j], 0.f);
  cr[j] = conv1_out[(size_t)root*DIM + j];
  __syncthreads();
  float s = 0.f;
  #pragma unroll 4
  for (int k = 0; k < DIM; k++) s += pr[k] * W2[(size_t)(DIM + k)*DIM + j];
  cvec[j] = s;
  cpool[j] = (j < 126) ? (cr[j] + cr[j+1] + cr[j+2]) * (1.f/3.f) : cr[j];
}

// conv2 aggregate + relu + fused avg-pool -> final out [N,254]
__global__ void k_conv2(const __half* __restrict__ xws, const int* __restrict__ csr_row,
                        const int* __restrict__ off, const int* __restrict__ cnt,
                        const float* __restrict__ dinv, const float* __restrict__ b2,
                        const float* __restrict__ cpool, float* __restrict__ out, int N){
  int wid  = (blockIdx.x*blockDim.x + threadIdx.x) >> 6;
  int lane = threadIdx.x & 63;
  if (wid >= N) return;
  int v = __builtin_amdgcn_readfirstlane(wid);
  float dv = dinv[v];
  const __half2* base = (const __half2*)xws;
  float2 s = __half22float2(base[(size_t)v*64 + lane]);
  float ax = s.x, ay = s.y;
  int o0 = off[v], c = cnt[v];
  int i = 0;
  for (; i + 4 <= c; i += 4){
    int r0 = csr_row[o0+i+0], r1 = csr_row[o0+i+1];
    int r2 = csr_row[o0+i+2], r3 = csr_row[o0+i+3];
    float2 f0 = __half22float2(base[(size_t)r0*64 + lane]);
    float2 f1 = __half22float2(base[(size_t)r1*64 + lane]);
    float2 f2 = __half22float2(base[(size_t)r2*64 + lane]);
    float2 f3 = __half22float2(base[(size_t)r3*64 + lane]);
    ax += (f0.x + f1.x) + (f2.x + f3.x);
    ay += (f0.y + f1.y) + (f2.y + f3.y);
  }
  for (; i < c; i++){
    int r = csr_row[o0+i];
    float2 f = __half22float2(base[(size_t)r*64 + lane]);
    ax += f.x; ay += f.y;
  }
  float2 bb = *(const float2*)(b2 + lane*2);
  float o0v = fmaxf(dv*ax + bb.x, 0.f);        // conv2_out[v][2*lane]
  float o1v = fmaxf(dv*ay + bb.y, 0.f);        // conv2_out[v][2*lane+1]

  // pooling: f = [conv1_root(128) | conv2_out(128)]; out col j = mean(f[j..j+2])
  float pa = __shfl_up(o0v, 1);                // o[2l-2]
  float pb = __shfl_up(o1v, 1);                // o[2l-1]
  if (lane == 0){ pa = cpool[126]; pb = cpool[127]; }   // cr[126], cr[127]
  float p0 = (pa + pb + o0v) * (1.f/3.f);      // col 126+2l
  float p1 = (pb + o0v + o1v) * (1.f/3.f);     // col 127+2l

  float* orow = out + (size_t)v*254;
  if (lane < 63){                               // const cols 0..125
    float2 cp = *(const float2*)(cpool + 2*lane);
    *(float2*)(orow + 2*lane) = cp;
  }
  *(float2*)(orow + 126 + 2*lane) = make_float2(p0, p1);
}

extern "C" void kernel_launch(void* const* d_in, const int* in_sizes, int n_in,
                              void* d_out, int out_size, void* d_ws, size_t ws_size,
                              hipStream_t stream){
  const float* posts = (const float*)d_in[0];
  const float* W1    = (const float*)d_in[1];
  const float* b1    = (const float*)d_in[2];
  const float* W2    = (const float*)d_in[3];
  const float* b2    = (const float*)d_in[4];
  const int*   eidx  = (const int*)d_in[5];
  const int*   rootI = (const int*)d_in[6];
  int N = in_sizes[0] / DIM;
  int E = in_sizes[5] / 2;
  const int* row = eidx;
  const int* col = eidx + E;

  char* p = (char*)d_ws;
  auto alloc = [&](size_t bytes)->void*{
    void* q = (void*)p; p += (bytes + 255) & ~(size_t)255; return q;
  };
  __half* xw1s  = (__half*)alloc((size_t)N*DIM*2);
  __half* xw2s  = (__half*)alloc((size_t)N*DIM*2);
  float* c1out  = (float*)alloc((size_t)N*DIM*4);
  float* dinv   = (float*)alloc((size_t)N*4);
  float* cvec   = (float*)alloc(DIM*4);
  float* cpool  = (float*)alloc(DIM*4);
  int*   cnt    = (int*)alloc((size_t)N*4);
  int*   off    = (int*)alloc((size_t)N*4);
  int*   cursor = (int*)alloc((size_t)N*4);
  int*   bsum   = (int*)alloc(512*4);
  int*   csrrow = (int*)alloc((size_t)E*4);

  hipMemsetAsync(cnt,    0, (size_t)N*4, stream);
  hipMemsetAsync(cursor, 0, (size_t)N*4, stream);

  int nb = (N + 255) / 256;
  k_count  <<<(E + 255)/256, 256, 0, stream>>>(col, E, cnt);
  k_scan1  <<<nb, 256, 0, stream>>>(cnt, off, bsum, N);
  k_scan2  <<<1, 512, 0, stream>>>(bsum, nb);
  k_scan3  <<<nb, 256, 0, stream>>>(off, bsum, cnt, dinv, N);
  k_scatter<<<(E + 255)/256, 256, 0, stream>>>(row, col, E, off, cursor, csrrow);

  k_gemm <<<(N + 63)/64, 256, 0, stream>>>(posts, W1, nullptr, dinv, xw1s, N, 0);
  k_conv1<<<(N + 3)/4, 256, 0, stream>>>(xw1s, csrrow, off, cnt, dinv, b1, c1out, N);
  k_small<<<1, 128, 0, stream>>>(posts, W2, c1out, rootI, cvec, cpool);
  k_gemm <<<(N + 63)/64, 256, 0, stream>>>(c1out, W2, cvec, dinv, xw2s, N, 1);
  k_conv2<<<(N + 3)/4, 256, 0, stream>>>(xw2s, csrrow, off, cnt, dinv, b2, cpool,
                                         (float*)d_out, N);
}